// Round 16
// baseline (92.355 us; speedup 1.0000x reference)
//
#include <hip/hip_runtime.h>

constexpr int K_CODES = 512;
constexpr int D_DIM   = 64;
constexpr int HW      = 4096;               // 64*64
constexpr int BATCH   = 32;
constexpr int N_ROWS  = BATCH * HW;         // 131072
constexpr int HALF    = BATCH * D_DIM * HW; // elements per output tensor
constexpr float MU    = 1e-4f;              // 5x over ~1.9e-5 approx-vs-ref spread
constexpr int TPB     = 512;                // 8 waves
constexpr int RPB     = 256;                // rows per block (8 waves x 32)

typedef __attribute__((ext_vector_type(8))) short bf16x8;
typedef __attribute__((ext_vector_type(4))) float f32x4;

__device__ __forceinline__ unsigned short f32_bf16_rn(float x) {
    unsigned u = __builtin_bit_cast(unsigned, x);
    unsigned r = (u + 0x7FFFu + ((u >> 16) & 1u)) >> 16;   // round-to-nearest-even
    return (unsigned short)r;
}
__device__ __forceinline__ float bf16_f32(unsigned short h) {
    unsigned u = ((unsigned)h) << 16;
    return __builtin_bit_cast(float, u);
}

// prep: ee[k]=|e_k|^2 (bit-exact sequential f32, = reference), interleaved
// two-term bf16 codebook ehl[k*128 + d]=hi, [.. +64+d]=lo, and transposed
// f32 codebook embT[d*512 + k] (for the coalesced exact slow path).
__global__ void prep(const float* __restrict__ emb, float* __restrict__ ee,
                     unsigned short* __restrict__ ehl, float* __restrict__ embT) {
#pragma clang fp contract(off)
    int k = blockIdx.x * 256 + threadIdx.x;
    if (k >= K_CODES) return;
    const float* w = emb + k * D_DIM;
    float acc = 0.f;
    for (int d = 0; d < D_DIM; ++d) {
        float v = w[d];
        float q = v * v; acc = acc + q;
        unsigned short h = f32_bf16_rn(v);
        ehl[k * 128 + d]      = h;
        ehl[k * 128 + 64 + d] = f32_bf16_rn(v - bf16_f32(h));
        embT[d * K_CODES + k] = v;
    }
    ee[k] = acc;
}

// ROUND-15 ALGORITHM (absmax 0.0, both validations) restructured for
// 2 blocks/CU: hi codebook half (64 KB) in LDS, lo half streamed from
// global (128 KB chip-wide, L2-resident). 512 thr = 8 waves, 66 KB LDS,
// grid 512 -> two independent blocks per CU cover each other's staging /
// barrier / epilogue phases (round 12-15 monolith had 1 block/CU, fully
// serialized phases, 62 us vs ~22 us busy-work).
// Numerics byte-identical: single-pass per-row top-2 via 16x16x32 bf16 MFMA,
// chains a0=hi*zh, a1=lo*zh, a2=hi*zl; MU-gap certificate; bit-exact
// coalesced slow path (sequential zz, d-ascending fma, first-occurrence).
__global__ __launch_bounds__(TPB, 4) void vq_persist(const float* __restrict__ zin,
                                                     const float* __restrict__ emb,
                                                     const float* __restrict__ ee,
                                                     const unsigned short* __restrict__ ehl,
                                                     const float* __restrict__ embT,
                                                     float* __restrict__ out) {
#pragma clang fp contract(off)
    __shared__ __attribute__((aligned(16))) short s_cb[K_CODES * 64]; // hi only, 64 KB
    __shared__ __attribute__((aligned(16))) float s_ee[K_CODES];      // 2 KB

    const int tid  = threadIdx.x;
    const int wid  = tid >> 6;           // 0..7
    const int lane = tid & 63;
    const int l15  = lane & 15;
    const int lq   = lane >> 4;          // 0..3 = k-quarter

    const int rowbase = blockIdx.x * RPB + wid * 32;

    // ---- issue z loads FIRST (f32, 32 per thread); complete under staging.
    // Layout (validated rounds 7-15): col = l15, k = s*32 + lq*8 + j.
    float rz[2][2][8];
#pragma unroll
    for (int rg = 0; rg < 2; ++rg) {
        const int n0 = rowbase + rg * 16 + l15;
        const float* zp = zin + (size_t)(n0 >> 12) * (D_DIM * HW) + (n0 & (HW - 1));
#pragma unroll
        for (int s = 0; s < 2; ++s)
#pragma unroll
            for (int j = 0; j < 8; ++j)
                rz[rg][s][j] = zp[(size_t)(s * 32 + lq * 8 + j) * HW];
    }

    // ---- stage hi codebook half (64 KB), swizzled for 128 B rows:
    // logical hi byte o: code = o>>7, within = o&127; source byte =
    // code*256 + within. LDS dest: c16=(o>>4)&7 -> (o&~127)|((c16^(code&7))<<4).
#pragma unroll
    for (int r = 0; r < 8; ++r) {
        const int o = r * (TPB * 16) + tid * 16;          // 0..65520
        const int code = o >> 7;
        const f32x4 v = *(const f32x4*)((const char*)ehl + code * 256 + (o & 127));
        const int c16 = (o >> 4) & 7;
        const int so  = (o & ~127) | ((c16 ^ (code & 7)) << 4);
        *(f32x4*)((char*)s_cb + so) = v;
    }
    s_ee[tid] = ee[tid];                 // 512 threads cover 512 entries
    __syncthreads();                     // the only barrier

    // ---- convert z to two-term bf16 fragments
    bf16x8 zh[2][2], zl[2][2];
#pragma unroll
    for (int rg = 0; rg < 2; ++rg)
#pragma unroll
        for (int s = 0; s < 2; ++s)
#pragma unroll
            for (int j = 0; j < 8; ++j) {
                const float v = rz[rg][s][j];
                const unsigned short h = f32_bf16_rn(v);
                zh[rg][s][j] = (short)h;
                zl[rg][s][j] = (short)f32_bf16_rn(v - bf16_f32(h));
            }

    // per-lane swizzled hi-fragment byte offsets: row = gct*16+l15 (128 B/row),
    // col16 = s*4 + lq (0..7), swizzled by row&7 = l15&7
    int fb[2];
#pragma unroll
    for (int s = 0; s < 2; ++s)
        fb[s] = l15 * 128 + (((s * 4 + lq) ^ (l15 & 7)) << 4);

    float m1[2] = {3.4e38f, 3.4e38f}, m2[2] = {3.4e38f, 3.4e38f};
    int   i1[2] = {0, 0};

#pragma unroll 4
    for (int gct = 0; gct < 32; ++gct) {
        const char* cb = (const char*)s_cb + gct * 2048;
        const bf16x8 ah0 = *(const bf16x8*)(cb + fb[0]);
        const bf16x8 ah1 = *(const bf16x8*)(cb + fb[1]);
        // lo fragments from global (ehl is 128 KB, L2-resident chip-wide)
        const char* gl = (const char*)ehl + (size_t)(gct * 16 + l15) * 256 + 128 + lq * 16;
        const bf16x8 al0 = *(const bf16x8*)(gl);
        const bf16x8 al1 = *(const bf16x8*)(gl + 64);
        const f32x4 ev = *(const f32x4*)&s_ee[gct * 16 + lq * 4];
#pragma unroll
        for (int rg = 0; rg < 2; ++rg) {
            f32x4 a0 = {0.f,0.f,0.f,0.f}, a1 = {0.f,0.f,0.f,0.f}, a2 = {0.f,0.f,0.f,0.f};
            a0 = __builtin_amdgcn_mfma_f32_16x16x32_bf16(ah0, zh[rg][0], a0, 0, 0, 0);
            a1 = __builtin_amdgcn_mfma_f32_16x16x32_bf16(al0, zh[rg][0], a1, 0, 0, 0);
            a2 = __builtin_amdgcn_mfma_f32_16x16x32_bf16(ah0, zl[rg][0], a2, 0, 0, 0);
            a0 = __builtin_amdgcn_mfma_f32_16x16x32_bf16(ah1, zh[rg][1], a0, 0, 0, 0);
            a1 = __builtin_amdgcn_mfma_f32_16x16x32_bf16(al1, zh[rg][1], a1, 0, 0, 0);
            a2 = __builtin_amdgcn_mfma_f32_16x16x32_bf16(ah1, zl[rg][1], a2, 0, 0, 0);
#pragma unroll
            for (int r = 0; r < 4; ++r) {
                const float ssum = (a0[r] + a1[r]) + a2[r];
                const float dist = __builtin_fmaf(-2.f, ssum, ev[r]);
                const float hi   = fmaxf(m1[rg], dist);
                m2[rg] = fminf(m2[rg], hi);
                i1[rg] = (dist < m1[rg]) ? (gct * 16 + lq * 4 + r) : i1[rg];
                m1[rg] = fminf(m1[rg], dist);
            }
        }
    }

    // merge top-2 across the 4 k-quarters; afterwards every lane holds the
    // final (m1,i1,m2) for row rg*16 + l15
#pragma unroll
    for (int rg = 0; rg < 2; ++rg) {
#pragma unroll
        for (int mk = 16; mk <= 32; mk <<= 1) {
            const float om1 = __shfl_xor(m1[rg], mk, 64);
            const float om2 = __shfl_xor(m2[rg], mk, 64);
            const int   oi  = __shfl_xor(i1[rg], mk, 64);
            const float hi  = fmaxf(m1[rg], om1);
            m2[rg] = fminf(fminf(m2[rg], om2), hi);
            i1[rg] = (om1 < m1[rg]) ? oi : i1[rg];
            m1[rg] = fminf(m1[rg], om1);
        }
    }

    int w[2] = {i1[0], i1[1]};           // winner per (rg, l15), kept in registers

#pragma unroll
    for (int rg = 0; rg < 2; ++rg) {
        const bool flagged = (m2[rg] <= m1[rg] + MU);
        unsigned long long fmask = __ballot(flagged) & 0xFFFFull;

        // slow path: bit-exact full scan for ambiguous rows, wave-cooperative.
        // Lane L owns codes L*8+j; embT reads fully coalesced (f32x4 pairs).
        while (fmask) {
            const int R = __builtin_ctzll(fmask);
            fmask &= fmask - 1;
            const int n = rowbase + rg * 16 + R;
            const float* zq = zin + (size_t)(n >> 12) * (D_DIM * HW) + (n & (HW - 1));

            float zz = 0.f;                         // sequential, separate rounding
            for (int d = 0; d < D_DIM; ++d) {
                const float v = zq[(size_t)d * HW]; // wave-uniform addr -> s_load
                const float q = v * v; zz = zz + q;
            }
            float dot[8];
#pragma unroll
            for (int j = 0; j < 8; ++j) dot[j] = 0.f;
            for (int d = 0; d < D_DIM; ++d) {
                const float zd = zq[(size_t)d * HW];
                const float* er = embT + d * K_CODES + lane * 8;
                const f32x4 e0 = *(const f32x4*)(er);
                const f32x4 e1 = *(const f32x4*)(er + 4);
#pragma unroll
                for (int j = 0; j < 4; ++j) {
                    dot[j]     = __builtin_fmaf(e0[j], zd, dot[j]);
                    dot[j + 4] = __builtin_fmaf(e1[j], zd, dot[j + 4]);
                }
            }
            float bd = 3.4e38f; int bidx = 0;
#pragma unroll
            for (int j = 0; j < 8; ++j) {
                const float mm = 2.0f * dot[j];
                const float s  = zz - mm;
                const float dist = s + s_ee[lane * 8 + j];
                if (dist < bd) { bd = dist; bidx = lane * 8 + j; }  // strict < : lowest j
            }
#pragma unroll
            for (int mk = 1; mk <= 32; mk <<= 1) {  // lexicographic (dist, idx) min
                const float od = __shfl_xor(bd, mk, 64);
                const int   oi = __shfl_xor(bidx, mk, 64);
                const bool take = (od < bd) || (od == bd && oi < bidx);
                bd   = take ? od : bd;
                bidx = take ? oi : bidx;
            }
            if ((lane & 15) == R) w[rg] = bidx;     // bidx uniform across wave
        }
    }

    // ---- epilogue (per-wave, no sync): lane covers row = lane&31 at
    // d-half lane>>5. Winner for that row is in this lane's w[(lane>>4)&1].
    const int myrow = lane & 31;
    const int win   = w[(lane >> 4) & 1];
    const int n2    = rowbase + myrow;
    const int d0    = (lane >> 5) * 32;
    float* o1 = out + (size_t)(n2 >> 12) * (D_DIM * HW) + (n2 & (HW - 1));
    float* o2 = o1 + HALF;
    const float* wv = emb + (size_t)win * D_DIM + d0;
#pragma unroll
    for (int q = 0; q < 8; ++q) {
        const f32x4 v = *(const f32x4*)(wv + q * 4);
#pragma unroll
        for (int i = 0; i < 4; ++i) {
            const int d = d0 + q * 4 + i;
            o1[(size_t)d * HW] = v[i];
            o2[(size_t)d * HW] = v[i];
        }
    }
}

// fallback (validated round-2 kernel) if ws too small
__global__ __launch_bounds__(256) void vq_fallback(const float* __restrict__ zin,
                                                   const float* __restrict__ emb,
                                                   float* __restrict__ out) {
#pragma clang fp contract(off)
    __shared__ float s_ee[K_CODES];
    const int tid = threadIdx.x;
    for (int k = tid; k < K_CODES; k += 256) {
        const float* w = emb + k * D_DIM;
        float acc = 0.f;
        for (int d = 0; d < D_DIM; ++d) { float q = w[d] * w[d]; acc = acc + q; }
        s_ee[k] = acc;
    }
    __syncthreads();
    const int n = blockIdx.x * 256 + tid;
    const int b = n >> 12;
    const int p = n & (HW - 1);
    const float* zp = zin + (size_t)b * (D_DIM * HW) + p;
    float zr[D_DIM];
#pragma unroll
    for (int d = 0; d < D_DIM; ++d) zr[d] = zp[(size_t)d * HW];
    float zz = 0.f;
#pragma unroll
    for (int d = 0; d < D_DIM; ++d) { float q = zr[d] * zr[d]; zz = zz + q; }
    float best = 3.4e38f; int bi = 0;
    for (int k0 = 0; k0 < K_CODES; k0 += 8) {
        const float* w = emb + (size_t)k0 * D_DIM;
        float dot[8];
#pragma unroll
        for (int j = 0; j < 8; ++j) dot[j] = 0.f;
#pragma unroll
        for (int d = 0; d < D_DIM; ++d) {
            const float z = zr[d];
#pragma unroll
            for (int j = 0; j < 8; ++j)
                dot[j] = __builtin_fmaf(w[j * D_DIM + d], z, dot[j]);
        }
#pragma unroll
        for (int j = 0; j < 8; ++j) {
            const float m = 2.0f * dot[j];
            const float s = zz - m;
            const float dist = s + s_ee[k0 + j];
            if (dist < best) { best = dist; bi = k0 + j; }
        }
    }
    const float* wb = emb + (size_t)bi * D_DIM;
    float* o1 = out + (size_t)b * (D_DIM * HW) + p;
    float* o2 = o1 + HALF;
#pragma unroll
    for (int d = 0; d < D_DIM; ++d) {
        const float v = wb[d];
        o1[(size_t)d * HW] = v;
        o2[(size_t)d * HW] = v;
    }
}

extern "C" void kernel_launch(void* const* d_in, const int* in_sizes, int n_in,
                              void* d_out, int out_size, void* d_ws, size_t ws_size,
                              hipStream_t stream) {
    const float* z   = (const float*)d_in[0];
    const float* emb = (const float*)d_in[1];
    float* out = (float*)d_out;

    const size_t EHL_B  = (size_t)K_CODES * 128 * sizeof(unsigned short); // 128 KB
    const size_t EMBT_B = (size_t)K_CODES * D_DIM * sizeof(float);        // 128 KB
    const size_t need = 2048 + EHL_B + EMBT_B;                            // 258 KB
    if (ws_size >= need) {
        float* ee = (float*)d_ws;
        unsigned short* ehl = (unsigned short*)((char*)d_ws + 2048);
        float* embT = (float*)((char*)d_ws + 2048 + EHL_B);
        hipLaunchKernelGGL(prep, dim3(2), dim3(256), 0, stream, emb, ee, ehl, embT);
        hipLaunchKernelGGL(vq_persist, dim3(N_ROWS / RPB), dim3(TPB), 0, stream,
                           z, emb, ee, ehl, embT, out);
    } else {
        hipLaunchKernelGGL(vq_fallback, dim3(N_ROWS / 256), dim3(256), 0, stream,
                           z, emb, out);
    }
}

// Round 17
// 84.376 us; speedup vs baseline: 1.0946x; 1.0946x over previous
//
#include <hip/hip_runtime.h>

constexpr int K_CODES = 512;
constexpr int D_DIM   = 64;
constexpr int HW      = 4096;               // 64*64
constexpr int BATCH   = 32;
constexpr int N_ROWS  = BATCH * HW;         // 131072
constexpr int HALF    = BATCH * D_DIM * HW; // elements per output tensor
constexpr float MU    = 1e-4f;              // 5x over ~1.9e-5 approx-vs-ref spread
constexpr int TPB     = 512;                // 8 waves
constexpr int RPB     = 256;                // rows per block (8 waves x 32)

typedef __attribute__((ext_vector_type(8))) short bf16x8;
typedef __attribute__((ext_vector_type(4))) float f32x4;

__device__ __forceinline__ unsigned short f32_bf16_rn(float x) {
    unsigned u = __builtin_bit_cast(unsigned, x);
    unsigned r = (u + 0x7FFFu + ((u >> 16) & 1u)) >> 16;   // round-to-nearest-even
    return (unsigned short)r;
}
__device__ __forceinline__ float bf16_f32(unsigned short h) {
    unsigned u = ((unsigned)h) << 16;
    return __builtin_bit_cast(float, u);
}

// prep: ee[k]=|e_k|^2 (bit-exact sequential f32, = reference), interleaved
// two-term bf16 codebook ehl[k*128 + d]=hi, [.. +64+d]=lo, and transposed
// f32 codebook embT[d*512 + k] (for the coalesced exact slow path).
__global__ void prep(const float* __restrict__ emb, float* __restrict__ ee,
                     unsigned short* __restrict__ ehl, float* __restrict__ embT) {
#pragma clang fp contract(off)
    int k = blockIdx.x * 256 + threadIdx.x;
    if (k >= K_CODES) return;
    const float* w = emb + k * D_DIM;
    float acc = 0.f;
    for (int d = 0; d < D_DIM; ++d) {
        float v = w[d];
        float q = v * v; acc = acc + q;
        unsigned short h = f32_bf16_rn(v);
        ehl[k * 128 + d]      = h;
        ehl[k * 128 + 64 + d] = f32_bf16_rn(v - bf16_f32(h));
        embT[d * K_CODES + k] = v;
    }
    ee[k] = acc;
}

// ROUND-15 ALGORITHM (absmax 0.0, both validations) with the codebook
// streamed through a 32 KB LDS window in 4 phases (128 codes each, hi+lo
// BOTH in LDS -- round 16's lo-from-global poisoned the loop with vmcnt
// stalls and is reverted). 512 thr = 8 waves, ~35 KB LDS -> multiple
// blocks/CU co-resident; resident blocks interleave phases so staging /
// barriers / epilogues hide under other blocks' MFMA work (round 12-15
// monolith serialized everything at 1 block/CU).
// Numerics byte-identical: single-pass per-row top-2 via 16x16x32 bf16 MFMA,
// two-term z/e split, MU-gap certificate, bit-exact coalesced slow path
// (sequential zz, d-ascending fma, first-occurrence argmin).
__global__ __launch_bounds__(TPB, 4) void vq_phase(const float* __restrict__ zin,
                                                   const float* __restrict__ emb,
                                                   const float* __restrict__ ee,
                                                   const unsigned short* __restrict__ ehl,
                                                   const float* __restrict__ embT,
                                                   float* __restrict__ out) {
#pragma clang fp contract(off)
    __shared__ __attribute__((aligned(16))) short s_cb[128 * 128];  // 32 KB window
    __shared__ __attribute__((aligned(16))) float s_ee[K_CODES];    // 2 KB

    const int tid  = threadIdx.x;
    const int wid  = tid >> 6;           // 0..7
    const int lane = tid & 63;
    const int l15  = lane & 15;
    const int lq   = lane >> 4;          // 0..3 = k-quarter

    const int rowbase = blockIdx.x * RPB + wid * 32;

    // ---- issue z loads FIRST (f32, 32 per thread); complete under staging.
    // Layout (validated rounds 7-15): col = l15, k = s*32 + lq*8 + j.
    float rz[2][2][8];
#pragma unroll
    for (int rg = 0; rg < 2; ++rg) {
        const int n0 = rowbase + rg * 16 + l15;
        const float* zp = zin + (size_t)(n0 >> 12) * (D_DIM * HW) + (n0 & (HW - 1));
#pragma unroll
        for (int s = 0; s < 2; ++s)
#pragma unroll
            for (int j = 0; j < 8; ++j)
                rz[rg][s][j] = zp[(size_t)(s * 32 + lq * 8 + j) * HW];
    }

    // z fragments (filled during phase 0, before the compute barrier)
    bf16x8 zh[2][2], zl[2][2];

    // per-lane swizzled fragment byte offsets: local row = lct*16 + l15
    // (256 B/row), col16 = h*8 + s*4 + lq, swizzled by row&7 = l15&7
    int fb[4];
#pragma unroll
    for (int h = 0; h < 2; ++h)
#pragma unroll
        for (int s = 0; s < 2; ++s)
            fb[h * 2 + s] = l15 * 256 + (((h * 8 + s * 4 + lq) ^ (l15 & 7)) << 4);

    float m1[2] = {3.4e38f, 3.4e38f}, m2[2] = {3.4e38f, 3.4e38f};
    int   i1[2] = {0, 0};

    for (int ph = 0; ph < 4; ++ph) {
        if (ph > 0) __syncthreads();     // previous phase fully consumed

        // stage 128 codes (32 KB): 4 x 16B per thread, swizzled LDS write
        // (swizzle math validated rounds 12/14/15)
        const char* src = (const char*)ehl + ph * 32768;
#pragma unroll
        for (int r = 0; r < 4; ++r) {
            const int o = r * (TPB * 16) + tid * 16;      // 0..32752
            const f32x4 v = *(const f32x4*)(src + o);
            const int row = o >> 8;
            const int c16 = (o >> 4) & 15;
            const int so  = (o & ~255) | ((c16 ^ (row & 7)) << 4);
            *(f32x4*)((char*)s_cb + so) = v;
        }
        if (ph == 0) {
            s_ee[tid] = ee[tid];         // 512 threads cover 512 entries
            // convert z to two-term bf16 fragments (overlaps staging stores)
#pragma unroll
            for (int rg = 0; rg < 2; ++rg)
#pragma unroll
                for (int s = 0; s < 2; ++s)
#pragma unroll
                    for (int j = 0; j < 8; ++j) {
                        const float v = rz[rg][s][j];
                        const unsigned short h = f32_bf16_rn(v);
                        zh[rg][s][j] = (short)h;
                        zl[rg][s][j] = (short)f32_bf16_rn(v - bf16_f32(h));
                    }
        }
        __syncthreads();                 // window staged

#pragma unroll 2
        for (int lct = 0; lct < 8; ++lct) {
            const int gct = ph * 8 + lct;
            const char* cb = (const char*)s_cb + lct * 4096;
            const bf16x8 ah0 = *(const bf16x8*)(cb + fb[0]);
            const bf16x8 ah1 = *(const bf16x8*)(cb + fb[1]);
            const bf16x8 al0 = *(const bf16x8*)(cb + fb[2]);
            const bf16x8 al1 = *(const bf16x8*)(cb + fb[3]);
            const f32x4 ev = *(const f32x4*)&s_ee[gct * 16 + lq * 4];
#pragma unroll
            for (int rg = 0; rg < 2; ++rg) {
                f32x4 a0 = {0.f,0.f,0.f,0.f}, a1 = {0.f,0.f,0.f,0.f}, a2 = {0.f,0.f,0.f,0.f};
                a0 = __builtin_amdgcn_mfma_f32_16x16x32_bf16(ah0, zh[rg][0], a0, 0, 0, 0);
                a1 = __builtin_amdgcn_mfma_f32_16x16x32_bf16(al0, zh[rg][0], a1, 0, 0, 0);
                a2 = __builtin_amdgcn_mfma_f32_16x16x32_bf16(ah0, zl[rg][0], a2, 0, 0, 0);
                a0 = __builtin_amdgcn_mfma_f32_16x16x32_bf16(ah1, zh[rg][1], a0, 0, 0, 0);
                a1 = __builtin_amdgcn_mfma_f32_16x16x32_bf16(al1, zh[rg][1], a1, 0, 0, 0);
                a2 = __builtin_amdgcn_mfma_f32_16x16x32_bf16(ah1, zl[rg][1], a2, 0, 0, 0);
#pragma unroll
                for (int r = 0; r < 4; ++r) {
                    const float ssum = (a0[r] + a1[r]) + a2[r];
                    const float dist = __builtin_fmaf(-2.f, ssum, ev[r]);
                    const float hi   = fmaxf(m1[rg], dist);
                    m2[rg] = fminf(m2[rg], hi);
                    i1[rg] = (dist < m1[rg]) ? (gct * 16 + lq * 4 + r) : i1[rg];
                    m1[rg] = fminf(m1[rg], dist);
                }
            }
        }
    }

    // merge top-2 across the 4 k-quarters; afterwards every lane holds the
    // final (m1,i1,m2) for row rg*16 + l15
#pragma unroll
    for (int rg = 0; rg < 2; ++rg) {
#pragma unroll
        for (int mk = 16; mk <= 32; mk <<= 1) {
            const float om1 = __shfl_xor(m1[rg], mk, 64);
            const float om2 = __shfl_xor(m2[rg], mk, 64);
            const int   oi  = __shfl_xor(i1[rg], mk, 64);
            const float hi  = fmaxf(m1[rg], om1);
            m2[rg] = fminf(fminf(m2[rg], om2), hi);
            i1[rg] = (om1 < m1[rg]) ? oi : i1[rg];
            m1[rg] = fminf(m1[rg], om1);
        }
    }

    int w[2] = {i1[0], i1[1]};           // winner per (rg, l15), kept in registers

#pragma unroll
    for (int rg = 0; rg < 2; ++rg) {
        const bool flagged = (m2[rg] <= m1[rg] + MU);
        unsigned long long fmask = __ballot(flagged) & 0xFFFFull;

        // slow path: bit-exact full scan for ambiguous rows, wave-cooperative.
        // Lane L owns codes L*8+j; embT reads fully coalesced (f32x4 pairs).
        while (fmask) {
            const int R = __builtin_ctzll(fmask);
            fmask &= fmask - 1;
            const int n = rowbase + rg * 16 + R;
            const float* zq = zin + (size_t)(n >> 12) * (D_DIM * HW) + (n & (HW - 1));

            float zz = 0.f;                         // sequential, separate rounding
            for (int d = 0; d < D_DIM; ++d) {
                const float v = zq[(size_t)d * HW]; // wave-uniform addr -> s_load
                const float q = v * v; zz = zz + q;
            }
            float dot[8];
#pragma unroll
            for (int j = 0; j < 8; ++j) dot[j] = 0.f;
            for (int d = 0; d < D_DIM; ++d) {
                const float zd = zq[(size_t)d * HW];
                const float* er = embT + d * K_CODES + lane * 8;
                const f32x4 e0 = *(const f32x4*)(er);
                const f32x4 e1 = *(const f32x4*)(er + 4);
#pragma unroll
                for (int j = 0; j < 4; ++j) {
                    dot[j]     = __builtin_fmaf(e0[j], zd, dot[j]);
                    dot[j + 4] = __builtin_fmaf(e1[j], zd, dot[j + 4]);
                }
            }
            float bd = 3.4e38f; int bidx = 0;
#pragma unroll
            for (int j = 0; j < 8; ++j) {
                const float mm = 2.0f * dot[j];
                const float s  = zz - mm;
                const float dist = s + s_ee[lane * 8 + j];
                if (dist < bd) { bd = dist; bidx = lane * 8 + j; }  // strict < : lowest j
            }
#pragma unroll
            for (int mk = 1; mk <= 32; mk <<= 1) {  // lexicographic (dist, idx) min
                const float od = __shfl_xor(bd, mk, 64);
                const int   oi = __shfl_xor(bidx, mk, 64);
                const bool take = (od < bd) || (od == bd && oi < bidx);
                bd   = take ? od : bd;
                bidx = take ? oi : bidx;
            }
            if ((lane & 15) == R) w[rg] = bidx;     // bidx uniform across wave
        }
    }

    // ---- epilogue (per-wave, no sync): lane covers row = lane&31 at
    // d-half lane>>5. Winner for that row is in this lane's w[(lane>>4)&1].
    const int myrow = lane & 31;
    const int win   = w[(lane >> 4) & 1];
    const int n2    = rowbase + myrow;
    const int d0    = (lane >> 5) * 32;
    float* o1 = out + (size_t)(n2 >> 12) * (D_DIM * HW) + (n2 & (HW - 1));
    float* o2 = o1 + HALF;
    const float* wv = emb + (size_t)win * D_DIM + d0;
#pragma unroll
    for (int q = 0; q < 8; ++q) {
        const f32x4 v = *(const f32x4*)(wv + q * 4);
#pragma unroll
        for (int i = 0; i < 4; ++i) {
            const int d = d0 + q * 4 + i;
            o1[(size_t)d * HW] = v[i];
            o2[(size_t)d * HW] = v[i];
        }
    }
}

// fallback (validated round-2 kernel) if ws too small
__global__ __launch_bounds__(256) void vq_fallback(const float* __restrict__ zin,
                                                   const float* __restrict__ emb,
                                                   float* __restrict__ out) {
#pragma clang fp contract(off)
    __shared__ float s_ee[K_CODES];
    const int tid = threadIdx.x;
    for (int k = tid; k < K_CODES; k += 256) {
        const float* w = emb + k * D_DIM;
        float acc = 0.f;
        for (int d = 0; d < D_DIM; ++d) { float q = w[d] * w[d]; acc = acc + q; }
        s_ee[k] = acc;
    }
    __syncthreads();
    const int n = blockIdx.x * 256 + tid;
    const int b = n >> 12;
    const int p = n & (HW - 1);
    const float* zp = zin + (size_t)b * (D_DIM * HW) + p;
    float zr[D_DIM];
#pragma unroll
    for (int d = 0; d < D_DIM; ++d) zr[d] = zp[(size_t)d * HW];
    float zz = 0.f;
#pragma unroll
    for (int d = 0; d < D_DIM; ++d) { float q = zr[d] * zr[d]; zz = zz + q; }
    float best = 3.4e38f; int bi = 0;
    for (int k0 = 0; k0 < K_CODES; k0 += 8) {
        const float* w = emb + (size_t)k0 * D_DIM;
        float dot[8];
#pragma unroll
        for (int j = 0; j < 8; ++j) dot[j] = 0.f;
#pragma unroll
        for (int d = 0; d < D_DIM; ++d) {
            const float z = zr[d];
#pragma unroll
            for (int j = 0; j < 8; ++j)
                dot[j] = __builtin_fmaf(w[j * D_DIM + d], z, dot[j]);
        }
#pragma unroll
        for (int j = 0; j < 8; ++j) {
            const float m = 2.0f * dot[j];
            const float s = zz - m;
            const float dist = s + s_ee[k0 + j];
            if (dist < best) { best = dist; bi = k0 + j; }
        }
    }
    const float* wb = emb + (size_t)bi * D_DIM;
    float* o1 = out + (size_t)b * (D_DIM * HW) + p;
    float* o2 = o1 + HALF;
#pragma unroll
    for (int d = 0; d < D_DIM; ++d) {
        const float v = wb[d];
        o1[(size_t)d * HW] = v;
        o2[(size_t)d * HW] = v;
    }
}

extern "C" void kernel_launch(void* const* d_in, const int* in_sizes, int n_in,
                              void* d_out, int out_size, void* d_ws, size_t ws_size,
                              hipStream_t stream) {
    const float* z   = (const float*)d_in[0];
    const float* emb = (const float*)d_in[1];
    float* out = (float*)d_out;

    const size_t EHL_B  = (size_t)K_CODES * 128 * sizeof(unsigned short); // 128 KB
    const size_t EMBT_B = (size_t)K_CODES * D_DIM * sizeof(float);        // 128 KB
    const size_t need = 2048 + EHL_B + EMBT_B;                            // 258 KB
    if (ws_size >= need) {
        float* ee = (float*)d_ws;
        unsigned short* ehl = (unsigned short*)((char*)d_ws + 2048);
        float* embT = (float*)((char*)d_ws + 2048 + EHL_B);
        hipLaunchKernelGGL(prep, dim3(2), dim3(256), 0, stream, emb, ee, ehl, embT);
        hipLaunchKernelGGL(vq_phase, dim3(N_ROWS / RPB), dim3(TPB), 0, stream,
                           z, emb, ee, ehl, embT, out);
    } else {
        hipLaunchKernelGGL(vq_fallback, dim3(N_ROWS / 256), dim3(256), 0, stream,
                           z, emb, out);
    }
}

// Round 18
// 68.541 us; speedup vs baseline: 1.3474x; 1.2310x over previous
//
#include <hip/hip_runtime.h>

constexpr int K_CODES = 512;
constexpr int D_DIM   = 64;
constexpr int HW      = 4096;               // 64*64
constexpr int BATCH   = 32;
constexpr int N_ROWS  = BATCH * HW;         // 131072
constexpr int HALF    = BATCH * D_DIM * HW; // elements per output tensor
constexpr float MU    = 1e-4f;              // 5x over ~1.9e-5 approx-vs-ref spread
constexpr int TPB     = 1024;               // 16 waves
constexpr int RPB     = 512;                // rows per block (16 waves x 32)

typedef __attribute__((ext_vector_type(8))) short bf16x8;
typedef __attribute__((ext_vector_type(4))) float f32x4;

__device__ __forceinline__ unsigned short f32_bf16_rn(float x) {
    unsigned u = __builtin_bit_cast(unsigned, x);
    unsigned r = (u + 0x7FFFu + ((u >> 16) & 1u)) >> 16;   // round-to-nearest-even
    return (unsigned short)r;
}
__device__ __forceinline__ float bf16_f32(unsigned short h) {
    unsigned u = ((unsigned)h) << 16;
    return __builtin_bit_cast(float, u);
}

// prep: ee[k]=|e_k|^2 (bit-exact sequential f32, = reference), interleaved
// two-term bf16 codebook ehl[k*128 + d]=hi, [.. +64+d]=lo, and transposed
// f32 codebook embT[d*512 + k] (for the coalesced exact slow path).
__global__ void prep(const float* __restrict__ emb, float* __restrict__ ee,
                     unsigned short* __restrict__ ehl, float* __restrict__ embT) {
#pragma clang fp contract(off)
    int k = blockIdx.x * 256 + threadIdx.x;
    if (k >= K_CODES) return;
    const float* w = emb + k * D_DIM;
    float acc = 0.f;
    for (int d = 0; d < D_DIM; ++d) {
        float v = w[d];
        float q = v * v; acc = acc + q;
        unsigned short h = f32_bf16_rn(v);
        ehl[k * 128 + d]      = h;
        ehl[k * 128 + 64 + d] = f32_bf16_rn(v - bf16_f32(h));
        embT[d * K_CODES + k] = v;
    }
    ee[k] = acc;
}

// ROUND-15 KERNEL (best: 65.7 us, both validations, absmax 0.0) with two
// scheduling-only changes:
//  1. Per-wave ROTATED gct order: wave w scans gct = (g + 2*wid) & 31.
//     Breaks the 16-wave lockstep that made all waves burst the same pipe
//     (LDS -> MFMA -> VALU) simultaneously. Safe: m1/m2 are order-independent
//     (exact min / 2nd-min); i1 is order-sensitive only under ties, and ties
//     imply m2 <= m1 + MU -> flagged -> ascending-k exact slow path decides.
//  2. Non-temporal epilogue stores: the 67 MB write stream no longer evicts
//     z / ehl from L2.
// Numerics byte-identical otherwise: single-pass per-row top-2 via 16x16x32
// bf16 MFMA, two-term z/e split, MU-gap certificate, bit-exact coalesced
// slow path (sequential zz, d-ascending fma, first-occurrence argmin).
__global__ __launch_bounds__(TPB, 4) void vq_persist(const float* __restrict__ zin,
                                                     const float* __restrict__ emb,
                                                     const float* __restrict__ ee,
                                                     const unsigned short* __restrict__ ehl,
                                                     const float* __restrict__ embT,
                                                     float* __restrict__ out) {
#pragma clang fp contract(off)
    __shared__ __attribute__((aligned(16))) short s_cb[K_CODES * 128]; // 128 KB
    __shared__ __attribute__((aligned(16))) float s_ee[K_CODES];       // 2 KB

    const int tid  = threadIdx.x;
    const int wid  = tid >> 6;           // 0..15
    const int lane = tid & 63;
    const int l15  = lane & 15;
    const int lq   = lane >> 4;          // 0..3 = k-quarter

    const int rowbase = blockIdx.x * RPB + wid * 32;

    // ---- issue z loads FIRST (f32, 32 per thread); complete under staging.
    // Layout (validated rounds 7-17): col = l15, k = s*32 + lq*8 + j.
    float rz[2][2][8];
#pragma unroll
    for (int rg = 0; rg < 2; ++rg) {
        const int n0 = rowbase + rg * 16 + l15;
        const float* zp = zin + (size_t)(n0 >> 12) * (D_DIM * HW) + (n0 & (HW - 1));
#pragma unroll
        for (int s = 0; s < 2; ++s)
#pragma unroll
            for (int j = 0; j < 8; ++j)
                rz[rg][s][j] = zp[(size_t)(s * 32 + lq * 8 + j) * HW];
    }

    // ---- stage whole codebook, swizzled: logical byte o (row=o>>8, c16=(o>>4)&15)
    // lands at (o & ~255) | ((c16 ^ (row&7)) << 4). 8 x 16B per thread.
#pragma unroll
    for (int r = 0; r < 8; ++r) {
        const int o = r * (TPB * 16) + tid * 16;
        const f32x4 v = *(const f32x4*)((const char*)ehl + o);
        const int row = o >> 8;
        const int c16 = (o >> 4) & 15;
        const int so  = (o & ~255) | ((c16 ^ (row & 7)) << 4);
        *(f32x4*)((char*)s_cb + so) = v;
    }
    if (tid < K_CODES) s_ee[tid] = ee[tid];
    __syncthreads();                     // the only barrier

    // ---- convert z to two-term bf16 fragments
    bf16x8 zh[2][2], zl[2][2];
#pragma unroll
    for (int rg = 0; rg < 2; ++rg)
#pragma unroll
        for (int s = 0; s < 2; ++s)
#pragma unroll
            for (int j = 0; j < 8; ++j) {
                const float v = rz[rg][s][j];
                const unsigned short h = f32_bf16_rn(v);
                zh[rg][s][j] = (short)h;
                zl[rg][s][j] = (short)f32_bf16_rn(v - bf16_f32(h));
            }

    // per-lane swizzled fragment byte offsets: row = gct*16+l15 (256 B/row),
    // col16 = h*8 + s*4 + lq, swizzled by row&7 = l15&7
    int fb[4];
#pragma unroll
    for (int h = 0; h < 2; ++h)
#pragma unroll
        for (int s = 0; s < 2; ++s)
            fb[h * 2 + s] = l15 * 256 + (((h * 8 + s * 4 + lq) ^ (l15 & 7)) << 4);

    float m1[2] = {3.4e38f, 3.4e38f}, m2[2] = {3.4e38f, 3.4e38f};
    int   i1[2] = {0, 0};

    const int grot = wid * 2;            // per-wave scan rotation (de-sync)

#pragma unroll 4
    for (int g = 0; g < 32; ++g) {
        const int gct = (g + grot) & 31;
        const char* cb = (const char*)s_cb + gct * 4096;
        const bf16x8 ah0 = *(const bf16x8*)(cb + fb[0]);
        const bf16x8 ah1 = *(const bf16x8*)(cb + fb[1]);
        const bf16x8 al0 = *(const bf16x8*)(cb + fb[2]);
        const bf16x8 al1 = *(const bf16x8*)(cb + fb[3]);
        const f32x4 ev = *(const f32x4*)&s_ee[gct * 16 + lq * 4];
#pragma unroll
        for (int rg = 0; rg < 2; ++rg) {
            f32x4 a0 = {0.f,0.f,0.f,0.f}, a1 = {0.f,0.f,0.f,0.f}, a2 = {0.f,0.f,0.f,0.f};
            a0 = __builtin_amdgcn_mfma_f32_16x16x32_bf16(ah0, zh[rg][0], a0, 0, 0, 0);
            a1 = __builtin_amdgcn_mfma_f32_16x16x32_bf16(al0, zh[rg][0], a1, 0, 0, 0);
            a2 = __builtin_amdgcn_mfma_f32_16x16x32_bf16(ah0, zl[rg][0], a2, 0, 0, 0);
            a0 = __builtin_amdgcn_mfma_f32_16x16x32_bf16(ah1, zh[rg][1], a0, 0, 0, 0);
            a1 = __builtin_amdgcn_mfma_f32_16x16x32_bf16(al1, zh[rg][1], a1, 0, 0, 0);
            a2 = __builtin_amdgcn_mfma_f32_16x16x32_bf16(ah1, zl[rg][1], a2, 0, 0, 0);
#pragma unroll
            for (int r = 0; r < 4; ++r) {
                const float ssum = (a0[r] + a1[r]) + a2[r];
                const float dist = __builtin_fmaf(-2.f, ssum, ev[r]);
                const float hi   = fmaxf(m1[rg], dist);
                m2[rg] = fminf(m2[rg], hi);
                i1[rg] = (dist < m1[rg]) ? (gct * 16 + lq * 4 + r) : i1[rg];
                m1[rg] = fminf(m1[rg], dist);
            }
        }
    }

    // merge top-2 across the 4 k-quarters; afterwards every lane holds the
    // final (m1,i1,m2) for row rg*16 + l15
#pragma unroll
    for (int rg = 0; rg < 2; ++rg) {
#pragma unroll
        for (int mk = 16; mk <= 32; mk <<= 1) {
            const float om1 = __shfl_xor(m1[rg], mk, 64);
            const float om2 = __shfl_xor(m2[rg], mk, 64);
            const int   oi  = __shfl_xor(i1[rg], mk, 64);
            const float hi  = fmaxf(m1[rg], om1);
            m2[rg] = fminf(fminf(m2[rg], om2), hi);
            i1[rg] = (om1 < m1[rg]) ? oi : i1[rg];
            m1[rg] = fminf(m1[rg], om1);
        }
    }

    int w[2] = {i1[0], i1[1]};           // winner per (rg, l15), kept in registers

#pragma unroll
    for (int rg = 0; rg < 2; ++rg) {
        const bool flagged = (m2[rg] <= m1[rg] + MU);
        unsigned long long fmask = __ballot(flagged) & 0xFFFFull;

        // slow path: bit-exact full scan for ambiguous rows, wave-cooperative.
        // Lane L owns codes L*8+j; embT reads fully coalesced (f32x4 pairs).
        while (fmask) {
            const int R = __builtin_ctzll(fmask);
            fmask &= fmask - 1;
            const int n = rowbase + rg * 16 + R;
            const float* zq = zin + (size_t)(n >> 12) * (D_DIM * HW) + (n & (HW - 1));

            float zz = 0.f;                         // sequential, separate rounding
            for (int d = 0; d < D_DIM; ++d) {
                const float v = zq[(size_t)d * HW]; // wave-uniform addr -> s_load
                const float q = v * v; zz = zz + q;
            }
            float dot[8];
#pragma unroll
            for (int j = 0; j < 8; ++j) dot[j] = 0.f;
            for (int d = 0; d < D_DIM; ++d) {
                const float zd = zq[(size_t)d * HW];
                const float* er = embT + d * K_CODES + lane * 8;
                const f32x4 e0 = *(const f32x4*)(er);
                const f32x4 e1 = *(const f32x4*)(er + 4);
#pragma unroll
                for (int j = 0; j < 4; ++j) {
                    dot[j]     = __builtin_fmaf(e0[j], zd, dot[j]);
                    dot[j + 4] = __builtin_fmaf(e1[j], zd, dot[j + 4]);
                }
            }
            float bd = 3.4e38f; int bidx = 0;
#pragma unroll
            for (int j = 0; j < 8; ++j) {
                const float mm = 2.0f * dot[j];
                const float s  = zz - mm;
                const float dist = s + s_ee[lane * 8 + j];
                if (dist < bd) { bd = dist; bidx = lane * 8 + j; }  // strict < : lowest j
            }
#pragma unroll
            for (int mk = 1; mk <= 32; mk <<= 1) {  // lexicographic (dist, idx) min
                const float od = __shfl_xor(bd, mk, 64);
                const int   oi = __shfl_xor(bidx, mk, 64);
                const bool take = (od < bd) || (od == bd && oi < bidx);
                bd   = take ? od : bd;
                bidx = take ? oi : bidx;
            }
            if ((lane & 15) == R) w[rg] = bidx;     // bidx uniform across wave
        }
    }

    // ---- epilogue (per-wave, no sync): lane covers row = lane&31 at
    // d-half lane>>5. Winner for that row is in this lane's w[(lane>>4)&1].
    // Non-temporal stores keep the 67 MB write stream out of L2.
    const int myrow = lane & 31;
    const int win   = w[(lane >> 4) & 1];
    const int n2    = rowbase + myrow;
    const int d0    = (lane >> 5) * 32;
    float* o1 = out + (size_t)(n2 >> 12) * (D_DIM * HW) + (n2 & (HW - 1));
    float* o2 = o1 + HALF;
    const float* wv = emb + (size_t)win * D_DIM + d0;
#pragma unroll
    for (int q = 0; q < 8; ++q) {
        const f32x4 v = *(const f32x4*)(wv + q * 4);
#pragma unroll
        for (int i = 0; i < 4; ++i) {
            const int d = d0 + q * 4 + i;
            __builtin_nontemporal_store(v[i], &o1[(size_t)d * HW]);
            __builtin_nontemporal_store(v[i], &o2[(size_t)d * HW]);
        }
    }
}

// fallback (validated round-2 kernel) if ws too small
__global__ __launch_bounds__(256) void vq_fallback(const float* __restrict__ zin,
                                                   const float* __restrict__ emb,
                                                   float* __restrict__ out) {
#pragma clang fp contract(off)
    __shared__ float s_ee[K_CODES];
    const int tid = threadIdx.x;
    for (int k = tid; k < K_CODES; k += 256) {
        const float* w = emb + k * D_DIM;
        float acc = 0.f;
        for (int d = 0; d < D_DIM; ++d) { float q = w[d] * w[d]; acc = acc + q; }
        s_ee[k] = acc;
    }
    __syncthreads();
    const int n = blockIdx.x * 256 + tid;
    const int b = n >> 12;
    const int p = n & (HW - 1);
    const float* zp = zin + (size_t)b * (D_DIM * HW) + p;
    float zr[D_DIM];
#pragma unroll
    for (int d = 0; d < D_DIM; ++d) zr[d] = zp[(size_t)d * HW];
    float zz = 0.f;
#pragma unroll
    for (int d = 0; d < D_DIM; ++d) { float q = zr[d] * zr[d]; zz = zz + q; }
    float best = 3.4e38f; int bi = 0;
    for (int k0 = 0; k0 < K_CODES; k0 += 8) {
        const float* w = emb + (size_t)k0 * D_DIM;
        float dot[8];
#pragma unroll
        for (int j = 0; j < 8; ++j) dot[j] = 0.f;
#pragma unroll
        for (int d = 0; d < D_DIM; ++d) {
            const float z = zr[d];
#pragma unroll
            for (int j = 0; j < 8; ++j)
                dot[j] = __builtin_fmaf(w[j * D_DIM + d], z, dot[j]);
        }
#pragma unroll
        for (int j = 0; j < 8; ++j) {
            const float m = 2.0f * dot[j];
            const float s = zz - m;
            const float dist = s + s_ee[k0 + j];
            if (dist < best) { best = dist; bi = k0 + j; }
        }
    }
    const float* wb = emb + (size_t)bi * D_DIM;
    float* o1 = out + (size_t)b * (D_DIM * HW) + p;
    float* o2 = o1 + HALF;
#pragma unroll
    for (int d = 0; d < D_DIM; ++d) {
        const float v = wb[d];
        o1[(size_t)d * HW] = v;
        o2[(size_t)d * HW] = v;
    }
}

extern "C" void kernel_launch(void* const* d_in, const int* in_sizes, int n_in,
                              void* d_out, int out_size, void* d_ws, size_t ws_size,
                              hipStream_t stream) {
    const float* z   = (const float*)d_in[0];
    const float* emb = (const float*)d_in[1];
    float* out = (float*)d_out;

    const size_t EHL_B  = (size_t)K_CODES * 128 * sizeof(unsigned short); // 128 KB
    const size_t EMBT_B = (size_t)K_CODES * D_DIM * sizeof(float);        // 128 KB
    const size_t need = 2048 + EHL_B + EMBT_B;                            // 258 KB
    if (ws_size >= need) {
        float* ee = (float*)d_ws;
        unsigned short* ehl = (unsigned short*)((char*)d_ws + 2048);
        float* embT = (float*)((char*)d_ws + 2048 + EHL_B);
        hipLaunchKernelGGL(prep, dim3(2), dim3(256), 0, stream, emb, ee, ehl, embT);
        hipLaunchKernelGGL(vq_persist, dim3(N_ROWS / RPB), dim3(TPB), 0, stream,
                           z, emb, ee, ehl, embT, out);
    } else {
        hipLaunchKernelGGL(vq_fallback, dim3(N_ROWS / 256), dim3(256), 0, stream,
                           z, emb, out);
    }
}